// Round 8
// baseline (5641.074 us; speedup 1.0000x reference)
//
#include <hip/hip_runtime.h>

#define BB 1024
#define NN 81
#define EE 1620
#define HH 128
#define G3 384
#define NSTEPS 8

#define HSTR 132     // hRM/smRM/hid row stride (floats)
#define ABSTR 260    // hAB row stride (floats)

typedef __attribute__((ext_vector_type(4))) float f32x4;

// ---- LDS float offsets ----
#define F_H     0            // hRM 81 x 132 = 10692
#define F_R2    10692        // 21060: union{ xs+win | hAB 81x260 | smRM 81x132 | hid 81x132 }
#define F_GOFF  31752        // 82 ints
#define F_GSEND 31834        // 1620 ushorts (810 float slots)
#define F_BM1   32644        // 128
#define F_BASE  32772        // 512
#define F_EXT   33284        // 512
#define F_TOT   33796
#define LDS_BYTES (F_TOT * 4)   // 135184 bytes

// ---------------------------------------------------------------------------
// prep_graph: CSR by receiver (int32 edge input) — verified R2/R4-R7.
// ---------------------------------------------------------------------------
__global__ __launch_bounds__(128) void prep_graph(const int* __restrict__ ei,
                                                  int* __restrict__ goff,
                                                  int* __restrict__ gsend) {
    __shared__ int eis[2 * EE];
    __shared__ int cs[NN];
    __shared__ int offs[NN + 1];
    int tid = threadIdx.x;
    for (int i = tid; i < 2 * EE; i += 128) eis[i] = ei[i];
    __syncthreads();
    if (tid < NN) {
        int c = 0;
        for (int e = 0; e < EE; e++) if (eis[EE + e] == tid) c++;
        cs[tid] = c;
    }
    __syncthreads();
    if (tid == 0) {
        int o = 0;
        for (int r = 0; r < NN; r++) { offs[r] = o; o += cs[r]; }
        offs[NN] = o;
    }
    __syncthreads();
    if (tid < NN) {
        int pos = offs[tid];
        for (int e = 0; e < EE; e++) {
            if (eis[EE + e] == tid) gsend[pos++] = eis[e];
        }
        goff[tid] = offs[tid];
    }
    if (tid == 0) goff[NN] = offs[NN];
}

// ---------------------------------------------------------------------------
// prep_wc: Wc[c][o] = sum_m W_ih[c][m] * W_m2[m][o]   (384 x 128)
// ---------------------------------------------------------------------------
__global__ __launch_bounds__(256) void prep_wc(const float* __restrict__ W_ih,
                                               const float* __restrict__ W_m2,
                                               float* __restrict__ Wc) {
    int idx = blockIdx.x * 256 + threadIdx.x;
    if (idx >= G3 * HH) return;
    int c = idx >> 7, o = idx & 127;
    float acc = 0.f;
    for (int m = 0; m < HH; m++) acc += W_ih[c * HH + m] * W_m2[m * HH + o];
    Wc[idx] = acc;
}

// ---------------------------------------------------------------------------
// prep_bias: base[512], ext[512]
// ---------------------------------------------------------------------------
__global__ __launch_bounds__(256) void prep_bias(const float* __restrict__ W_ih,
                                                 const float* __restrict__ b_m2,
                                                 const float* __restrict__ b_ih,
                                                 const float* __restrict__ b_hh,
                                                 float* __restrict__ basev,
                                                 float* __restrict__ extv) {
    int c = blockIdx.x * 256 + threadIdx.x;
    if (c >= 512) return;
    float base, ext;
    if (c < 384) {
        float bwc = 0.f;
        for (int m = 0; m < HH; m++) bwc += W_ih[c * HH + m] * b_m2[m];
        ext = bwc;
        base = (c < 256) ? (b_ih[c] + b_hh[c]) : b_ih[c];
    } else {
        ext = 0.f;
        base = b_hh[c - 128];
    }
    basev[c] = base;
    extv[c] = ext;
}

// ---------------------------------------------------------------------------
// prep_w1t: W1t[k][c] (128 x 256)
// ---------------------------------------------------------------------------
__global__ __launch_bounds__(256) void prep_w1t(const float* __restrict__ W_m1,
                                                float* __restrict__ W1t) {
    int idx = blockIdx.x * 256 + threadIdx.x;
    if (idx >= 128 * 256) return;
    int k = idx >> 8, c = idx & 255;
    W1t[idx] = (c < 128) ? W_m1[c * 256 + k] : W_m1[(c - 128) * 256 + 128 + k];
}

// ---------------------------------------------------------------------------
// prep_wg2: Wg2[k][c] (256 x 384): k<128 -> Wc[c][k] ; else W_hh[c][k-128]
// ---------------------------------------------------------------------------
__global__ __launch_bounds__(256) void prep_wg2(const float* __restrict__ Wc,
                                                const float* __restrict__ W_hh,
                                                float* __restrict__ Wg2) {
    int idx = blockIdx.x * 256 + threadIdx.x;
    if (idx >= 256 * G3) return;
    int k = idx / G3;
    int c = idx - k * G3;
    Wg2[idx] = (k < 128) ? Wc[c * HH + k] : W_hh[c * HH + (k - 128)];
}

// ---------------------------------------------------------------------------
// prep_wo1t: Wo1t[k][c] = W_o1[c][k]   (128 x 128)
// ---------------------------------------------------------------------------
__global__ __launch_bounds__(256) void prep_wo1t(const float* __restrict__ W_o1,
                                                 float* __restrict__ Wo1t) {
    int idx = blockIdx.x * 256 + threadIdx.x;
    if (idx >= 128 * 128) return;
    int k = idx >> 7, c = idx & 127;
    Wo1t[idx] = W_o1[c * HH + k];
}

// ---------------------------------------------------------------------------
// fused_rrn: one workgroup per puzzle, 1024 threads (16 waves), fp32.
// __launch_bounds__(1024, 4): 4 waves/EU min = 1 block/CU (LDS forces this
// anyway) -> VGPR cap 128, no spills (R7 had 64-cap spills, WRITE_SIZE 92MB).
// Per step: ONE pass over h computes hAB (W1 cols c,128+c) AND gh gates
// (W_hh cols c,128+c,256+c) -> 55 accums; edge agg; gi pass over sm; GRU.
// ---------------------------------------------------------------------------
__global__ __launch_bounds__(1024, 4) void fused_rrn(
    const float* __restrict__ x,
    const float* __restrict__ W_in, const float* __restrict__ b_in,
    const float* __restrict__ b_m1,
    const float* __restrict__ W1t, const float* __restrict__ Wg2,
    const float* __restrict__ basev, const float* __restrict__ extv,
    const float* __restrict__ Wo1t, const float* __restrict__ b_o1,
    const float* __restrict__ W_o2, const float* __restrict__ b_o2,
    const int* __restrict__ goff_g, const int* __restrict__ gsend_g,
    float* __restrict__ out)
{
    extern __shared__ float smf[];
    float* hRM  = smf + F_H;
    float* reg2 = smf + F_R2;
    int*   goffL = (int*)(smf + F_GOFF);
    unsigned short* gsendL = (unsigned short*)(smf + F_GSEND);
    float* bm1L  = smf + F_BM1;
    float* baseL = smf + F_BASE;
    float* extL  = smf + F_EXT;

    const int t  = threadIdx.x;
    const int b  = blockIdx.x;
    const int c  = t & 127;           // gate column
    const int g  = t >> 7;            // row group 0..7
    const int rowBase = g * 10;
    const int nR = (g == 7) ? 11 : 10;
    const int rW = t & 31;            // edge-phase row lane
    const int q  = t >> 5;            // edge-phase feat quad
    const int fq = 4 * q;

    // ---- stage misc + x/W_in (into reg2; used once) ----
    float* xsL  = reg2;          // 810
    float* winL = reg2 + 810;    // 1280
    for (int i = t; i < NN + 1; i += 1024) goffL[i] = goff_g[i];
    for (int i = t; i < EE; i += 1024) gsendL[i] = (unsigned short)gsend_g[i];
    if (t < 512) { baseL[t] = basev[t]; extL[t] = extv[t]; }
    if (t < 128) bm1L[t] = b_m1[t];
    for (int i = t; i < NN * 10; i += 1024) xsL[i] = x[(long)b * (NN * 10) + i];
    for (int i = t; i < HH * 10; i += 1024) winL[i] = W_in[i];
    __syncthreads();

    // ---- input projection: hRM[r][m] ----
    for (int idx = t; idx < NN * HH; idx += 1024) {
        int r = idx >> 7, m = idx & 127;
        float acc = b_in[m];
#pragma unroll
        for (int k = 0; k < 10; k++) acc += xsL[r * 10 + k] * winL[m * 10 + k];
        hRM[r * HSTR + m] = acc;
    }
    __syncthreads();

    // ======================= 8 message-passing steps =======================
    for (int step = 0; step < NSTEPS; step++) {
        float ghr[11], ghz[11], ghn[11];
        // ---------- fused pass over h: hAB cols {c,128+c} + gh gates ----------
        {
            float accA[11], accB[11];
#pragma unroll
            for (int i = 0; i < 11; i++) {
                accA[i] = 0.f; accB[i] = 0.f;
                ghr[i] = 0.f; ghz[i] = 0.f; ghn[i] = 0.f;
            }
            for (int kc = 0; kc < 128; kc += 4) {
                float bA[4], bB[4], bR[4], bZ[4], bN[4];
#pragma unroll
                for (int j = 0; j < 4; j++) {
                    const float* Bk1 = W1t + (kc + j) * 256;
                    bA[j] = Bk1[c];
                    bB[j] = Bk1[128 + c];
                    const float* Bk2 = Wg2 + (128 + kc + j) * G3;
                    bR[j] = Bk2[c];
                    bZ[j] = Bk2[128 + c];
                    bN[j] = Bk2[256 + c];
                }
#pragma unroll
                for (int i = 0; i < 11; i++) {
                    if (i < nR) {
                        f32x4 a = *(const f32x4*)(hRM + (rowBase + i) * HSTR + kc);
#pragma unroll
                        for (int j = 0; j < 4; j++) {
                            accA[i] = fmaf(a[j], bA[j], accA[i]);
                            accB[i] = fmaf(a[j], bB[j], accB[i]);
                            ghr[i]  = fmaf(a[j], bR[j], ghr[i]);
                            ghz[i]  = fmaf(a[j], bZ[j], ghz[i]);
                            ghn[i]  = fmaf(a[j], bN[j], ghn[i]);
                        }
                    }
                }
            }
            float* hAB = reg2;
#pragma unroll
            for (int i = 0; i < 11; i++) {
                if (i < nR) {
                    int row = rowBase + i;
                    hAB[row * ABSTR + c] = accA[i];
                    hAB[row * ABSTR + 128 + c] = accB[i];
                }
            }
        }
        __syncthreads();   // B1: hAB ready

        // ---------- edge aggregation (feature quad fq per lane) ----------
        float sv[3][4];
        {
            float bq[4];
#pragma unroll
            for (int j = 0; j < 4; j++) bq[j] = bm1L[fq + j];
#pragma unroll
            for (int s = 0; s < 3; s++) {
                int row = rW + 32 * s;
                if (row >= NN) { sv[s][0] = sv[s][1] = sv[s][2] = sv[s][3] = 0.f; continue; }
                int e0 = goffL[row], e1 = goffL[row + 1];
                f32x4 hb = *(const f32x4*)(reg2 + row * ABSTR + 128 + fq);
                float hbb[4], ac[4];
#pragma unroll
                for (int j = 0; j < 4; j++) { hbb[j] = hb[j] + bq[j]; ac[j] = 0.f; }
                for (int e = e0; e < e1; e++) {
                    int sn = gsendL[e];
                    f32x4 av = *(const f32x4*)(reg2 + sn * ABSTR + fq);
#pragma unroll
                    for (int j = 0; j < 4; j++) ac[j] += fmaxf(av[j] + hbb[j], 0.f);
                }
#pragma unroll
                for (int j = 0; j < 4; j++) sv[s][j] = ac[j];
            }
        }
        __syncthreads();   // B2: hAB reads done, reg2 reusable as smRM
        {
#pragma unroll
            for (int s = 0; s < 3; s++) {
                int row = rW + 32 * s;
                if (row >= NN) continue;
                f32x4 svv = {sv[s][0], sv[s][1], sv[s][2], sv[s][3]};
                *(f32x4*)(reg2 + row * HSTR + fq) = svv;
            }
        }
        __syncthreads();   // B3: smRM ready

        // ---------- gi pass: A = sm, B rows 0..127 -> rr, zz, ni ----------
        {
            float rr[11], zz[11], ni[11];
#pragma unroll
            for (int i = 0; i < 11; i++) { rr[i] = 0.f; zz[i] = 0.f; ni[i] = 0.f; }
            const float* smRM = reg2;
            for (int kc = 0; kc < 128; kc += 4) {
                float bR[4], bZ[4], bN[4];
#pragma unroll
                for (int j = 0; j < 4; j++) {
                    const float* Bk = Wg2 + (kc + j) * G3;
                    bR[j] = Bk[c];
                    bZ[j] = Bk[128 + c];
                    bN[j] = Bk[256 + c];
                }
#pragma unroll
                for (int i = 0; i < 11; i++) {
                    if (i < nR) {
                        f32x4 a = *(const f32x4*)(smRM + (rowBase + i) * HSTR + kc);
#pragma unroll
                        for (int j = 0; j < 4; j++) {
                            rr[i] = fmaf(a[j], bR[j], rr[i]);
                            zz[i] = fmaf(a[j], bZ[j], zz[i]);
                            ni[i] = fmaf(a[j], bN[j], ni[i]);
                        }
                    }
                }
            }

            // ---- GRU epilogue: thread updates h[row][c] (disjoint ownership) ----
            const float base0 = baseL[c],       ext0 = extL[c];
            const float base1 = baseL[128 + c], ext1 = extL[128 + c];
            const float base2 = baseL[256 + c], ext2 = extL[256 + c];
            const float base3 = baseL[384 + c];
#pragma unroll
            for (int i = 0; i < 11; i++) {
                if (i < nR) {
                    int row = rowBase + i;
                    float cf = (float)(goffL[row + 1] - goffL[row]);
                    float g0 = rr[i] + ghr[i] + base0 + cf * ext0;
                    float g1 = zz[i] + ghz[i] + base1 + cf * ext1;
                    float g2 = ni[i] + base2 + cf * ext2;
                    float g3 = ghn[i] + base3;
                    float rg_ = 1.f / (1.f + __expf(-g0));
                    float z   = 1.f / (1.f + __expf(-g1));
                    float npre = g2 + rg_ * g3;
                    float ax = fabsf(npre);
                    float e  = __expf(-2.f * ax);
                    float tt = (1.f - e) / (1.f + e);
                    float n  = copysignf(tt, npre);
                    float ho = hRM[row * HSTR + c];
                    hRM[row * HSTR + c] = (1.f - z) * n + z * ho;
                }
            }
        }
        __syncthreads();   // B5: smRM reads done + new h visible
    }

    // ======================= output head =======================
    // hid = relu(h @ W_o1^T + b_o1): thread (g,c) -> col c, its rows
    {
        float acc3[11];
#pragma unroll
        for (int i = 0; i < 11; i++) acc3[i] = 0.f;
        for (int kc = 0; kc < 128; kc += 4) {
            float bb[4];
#pragma unroll
            for (int j = 0; j < 4; j++) bb[j] = Wo1t[(kc + j) * 128 + c];
#pragma unroll
            for (int i = 0; i < 11; i++) {
                if (i < nR) {
                    f32x4 a = *(const f32x4*)(hRM + (rowBase + i) * HSTR + kc);
#pragma unroll
                    for (int j = 0; j < 4; j++) acc3[i] = fmaf(a[j], bb[j], acc3[i]);
                }
            }
        }
        float bo = b_o1[c];
        __syncthreads();   // hRM reads done; reg2 -> hid
#pragma unroll
        for (int i = 0; i < 11; i++) {
            if (i < nR) {
                int row = rowBase + i;
                reg2[row * HSTR + c] = fmaxf(acc3[i] + bo, 0.f);
            }
        }
    }
    __syncthreads();
    // stage W_o2/b_o2 into hRM area (dead)
    {
        float* wo2L = hRM;
        float* bo2L = hRM + 1152;
        for (int i = t; i < 9 * HH; i += 1024) wo2L[i] = W_o2[i];
        if (t < 9) bo2L[t] = b_o2[t];
    }
    __syncthreads();
    {
        const float* wo2L = hRM;
        const float* bo2L = hRM + 1152;
        for (int idx = t; idx < NN * 9; idx += 1024) {
            int r = idx / 9, qq = idx - 9 * r;
            float acc = bo2L[qq];
            const float* hrow = reg2 + r * HSTR;
            const float* wrow = wo2L + qq * HH;
            for (int k = 0; k < HH; k++) acc = fmaf(hrow[k], wrow[k], acc);
            out[((long)b * NN + r) * 9 + qq] = acc;
        }
    }
}

// ---------------------------------------------------------------------------
extern "C" void kernel_launch(void* const* d_in, const int* in_sizes, int n_in,
                              void* d_out, int out_size, void* d_ws, size_t ws_size,
                              hipStream_t stream) {
    const float* x      = (const float*)d_in[0];
    const int* ei       = (const int*)d_in[1];
    const float* W_in   = (const float*)d_in[2];
    const float* b_in   = (const float*)d_in[3];
    const float* W_m1   = (const float*)d_in[4];
    const float* b_m1   = (const float*)d_in[5];
    const float* W_m2   = (const float*)d_in[6];
    const float* b_m2   = (const float*)d_in[7];
    const float* W_ih   = (const float*)d_in[8];
    const float* W_hh   = (const float*)d_in[9];
    const float* b_ih   = (const float*)d_in[10];
    const float* b_hh   = (const float*)d_in[11];
    const float* W_o1   = (const float*)d_in[12];
    const float* b_o1   = (const float*)d_in[13];
    const float* W_o2   = (const float*)d_in[14];
    const float* b_o2   = (const float*)d_in[15];
    float* out = (float*)d_out;

    char* ws = (char*)d_ws;
    size_t off = 0;
    auto alloc = [&](size_t bytes) -> char* {
        char* p = ws + off;
        off += (bytes + 255) & ~(size_t)255;
        return p;
    };
    float* Wc    = (float*)alloc((size_t)G3 * HH * 4);
    float* W1t   = (float*)alloc(128 * 256 * 4);
    float* Wg2   = (float*)alloc(256 * G3 * 4);
    float* Wo1t  = (float*)alloc(128 * 128 * 4);
    float* basev = (float*)alloc(512 * 4);
    float* extv  = (float*)alloc(512 * 4);
    int* goff    = (int*)alloc((NN + 1) * 4);
    int* gsend   = (int*)alloc(EE * 4);

    prep_graph<<<1, 128, 0, stream>>>(ei, goff, gsend);
    prep_wc<<<(G3 * HH + 255) / 256, 256, 0, stream>>>(W_ih, W_m2, Wc);
    prep_bias<<<2, 256, 0, stream>>>(W_ih, b_m2, b_ih, b_hh, basev, extv);
    prep_w1t<<<128, 256, 0, stream>>>(W_m1, W1t);
    prep_wg2<<<(256 * G3 + 255) / 256, 256, 0, stream>>>(Wc, W_hh, Wg2);
    prep_wo1t<<<64, 256, 0, stream>>>(W_o1, Wo1t);

    (void)hipFuncSetAttribute((const void*)fused_rrn,
                              hipFuncAttributeMaxDynamicSharedMemorySize,
                              (int)LDS_BYTES);
    fused_rrn<<<BB, 1024, LDS_BYTES, stream>>>(
        x, W_in, b_in, b_m1, W1t, Wg2, basev, extv,
        Wo1t, b_o1, W_o2, b_o2, goff, gsend, out);
}

// Round 9
// 5478.687 us; speedup vs baseline: 1.0296x; 1.0296x over previous
//
#include <hip/hip_runtime.h>

#define BB 1024
#define NN 81
#define EE 1620
#define HH 128
#define G3 384
#define NSTEPS 8

#define HSTR 132     // hRM/smRM/hid row stride (floats)
#define ABSTR 260    // hAB row stride (floats)

typedef __attribute__((ext_vector_type(4))) float f32x4;

// ---- LDS float offsets ----
#define F_H     0            // hRM 81 x 132 = 10692
#define F_R2    10692        // 21060: union{ xs+win | hAB 81x260 | smRM 81x132 | hid 81x132 }
#define F_GOFF  31752        // 82 ints
#define F_GSEND 31834        // 1620 ushorts (810 float slots)
#define F_BM1   32644        // 128
#define F_BASE  32772        // 512
#define F_EXT   33284        // 512
#define F_TOT   33796
#define LDS_BYTES (F_TOT * 4)   // 135184 bytes

// ---------------------------------------------------------------------------
// prep_graph: CSR by receiver (int32 edge input) — verified R2/R4-R8.
// ---------------------------------------------------------------------------
__global__ __launch_bounds__(128) void prep_graph(const int* __restrict__ ei,
                                                  int* __restrict__ goff,
                                                  int* __restrict__ gsend) {
    __shared__ int eis[2 * EE];
    __shared__ int cs[NN];
    __shared__ int offs[NN + 1];
    int tid = threadIdx.x;
    for (int i = tid; i < 2 * EE; i += 128) eis[i] = ei[i];
    __syncthreads();
    if (tid < NN) {
        int c = 0;
        for (int e = 0; e < EE; e++) if (eis[EE + e] == tid) c++;
        cs[tid] = c;
    }
    __syncthreads();
    if (tid == 0) {
        int o = 0;
        for (int r = 0; r < NN; r++) { offs[r] = o; o += cs[r]; }
        offs[NN] = o;
    }
    __syncthreads();
    if (tid < NN) {
        int pos = offs[tid];
        for (int e = 0; e < EE; e++) {
            if (eis[EE + e] == tid) gsend[pos++] = eis[e];
        }
        goff[tid] = offs[tid];
    }
    if (tid == 0) goff[NN] = offs[NN];
}

// ---------------------------------------------------------------------------
// prep_wc: Wc[c][o] = sum_m W_ih[c][m] * W_m2[m][o]   (384 x 128)
// ---------------------------------------------------------------------------
__global__ __launch_bounds__(256) void prep_wc(const float* __restrict__ W_ih,
                                               const float* __restrict__ W_m2,
                                               float* __restrict__ Wc) {
    int idx = blockIdx.x * 256 + threadIdx.x;
    if (idx >= G3 * HH) return;
    int c = idx >> 7, o = idx & 127;
    float acc = 0.f;
    for (int m = 0; m < HH; m++) acc += W_ih[c * HH + m] * W_m2[m * HH + o];
    Wc[idx] = acc;
}

// ---------------------------------------------------------------------------
// prep_bias: base[512], ext[512]
// ---------------------------------------------------------------------------
__global__ __launch_bounds__(256) void prep_bias(const float* __restrict__ W_ih,
                                                 const float* __restrict__ b_m2,
                                                 const float* __restrict__ b_ih,
                                                 const float* __restrict__ b_hh,
                                                 float* __restrict__ basev,
                                                 float* __restrict__ extv) {
    int c = blockIdx.x * 256 + threadIdx.x;
    if (c >= 512) return;
    float base, ext;
    if (c < 384) {
        float bwc = 0.f;
        for (int m = 0; m < HH; m++) bwc += W_ih[c * HH + m] * b_m2[m];
        ext = bwc;
        base = (c < 256) ? (b_ih[c] + b_hh[c]) : b_ih[c];
    } else {
        ext = 0.f;
        base = b_hh[c - 128];
    }
    basev[c] = base;
    extv[c] = ext;
}

// ---------------------------------------------------------------------------
// prep_w1q: quad-packed W1: W1q[((k>>2)*256 + c)*4 + (k&3)] = W1[c][k]
//   W1[c][k] = c<128 ? W_m1[c][k] : W_m1[c-128][128+k]
// ---------------------------------------------------------------------------
__global__ __launch_bounds__(256) void prep_w1q(const float* __restrict__ W_m1,
                                                float* __restrict__ W1q) {
    int idx = blockIdx.x * 256 + threadIdx.x;   // 128*256
    if (idx >= 128 * 256) return;
    int k = idx >> 8, c = idx & 255;
    float v = (c < 128) ? W_m1[c * 256 + k] : W_m1[(c - 128) * 256 + 128 + k];
    W1q[((k >> 2) * 256 + c) * 4 + (k & 3)] = v;
}

// ---------------------------------------------------------------------------
// prep_wgq: quad-packed gates: Wgq[((k>>2)*384 + c)*4 + (k&3)]
//   = k<128 ? Wc[c][k] : W_hh[c][k-128]      (k in [0,256))
// ---------------------------------------------------------------------------
__global__ __launch_bounds__(256) void prep_wgq(const float* __restrict__ Wc,
                                                const float* __restrict__ W_hh,
                                                float* __restrict__ Wgq) {
    int idx = blockIdx.x * 256 + threadIdx.x;   // 256*384
    if (idx >= 256 * G3) return;
    int k = idx / G3;
    int c = idx - k * G3;
    float v = (k < 128) ? Wc[c * HH + k] : W_hh[c * HH + (k - 128)];
    Wgq[((k >> 2) * G3 + c) * 4 + (k & 3)] = v;
}

// ---------------------------------------------------------------------------
// prep_wo1q: Wo1q[((k>>2)*128 + c)*4 + (k&3)] = W_o1[c][k]
// ---------------------------------------------------------------------------
__global__ __launch_bounds__(256) void prep_wo1q(const float* __restrict__ W_o1,
                                                 float* __restrict__ Wo1q) {
    int idx = blockIdx.x * 256 + threadIdx.x;
    if (idx >= 128 * 128) return;
    int k = idx >> 7, c = idx & 127;
    Wo1q[((k >> 2) * 128 + c) * 4 + (k & 3)] = W_o1[c * HH + k];
}

// ---------------------------------------------------------------------------
// fused_rrn: one workgroup per puzzle, 1024 threads (16 waves), fp32.
// amdgpu_waves_per_eu(4,4): LDS forces 1 block/CU = 4 waves/EU exactly; pin
// the allocator there so it uses up to 128 VGPRs (R7/R8 spilled at 64-cap:
// launch_bounds' 2nd arg is only a MIN, compiler still targeted 8/EU).
// Per step: ONE pass over h computes hAB (W1 cols c,128+c) AND gh gates
// (W_hh cols c,128+c,256+c) = 55 accums; edge agg; gi pass over sm; GRU.
// B loads are quad-packed dwordx4, coalesced 1KB/wave-inst.
// ---------------------------------------------------------------------------
__global__ __launch_bounds__(1024)
__attribute__((amdgpu_waves_per_eu(4, 4)))
void fused_rrn(
    const float* __restrict__ x,
    const float* __restrict__ W_in, const float* __restrict__ b_in,
    const float* __restrict__ b_m1,
    const float* __restrict__ W1q, const float* __restrict__ Wgq,
    const float* __restrict__ basev, const float* __restrict__ extv,
    const float* __restrict__ Wo1q, const float* __restrict__ b_o1,
    const float* __restrict__ W_o2, const float* __restrict__ b_o2,
    const int* __restrict__ goff_g, const int* __restrict__ gsend_g,
    float* __restrict__ out)
{
    extern __shared__ float smf[];
    float* hRM  = smf + F_H;
    float* reg2 = smf + F_R2;
    int*   goffL = (int*)(smf + F_GOFF);
    unsigned short* gsendL = (unsigned short*)(smf + F_GSEND);
    float* bm1L  = smf + F_BM1;
    float* baseL = smf + F_BASE;
    float* extL  = smf + F_EXT;

    const int t  = threadIdx.x;
    const int b  = blockIdx.x;
    const int c  = t & 127;           // gate column
    const int g  = t >> 7;            // row group 0..7
    const int rowBase = g * 10;
    const int nR = (g == 7) ? 11 : 10;
    const int rW = t & 31;            // edge-phase row lane
    const int q  = t >> 5;            // edge-phase feat quad
    const int fq = 4 * q;

    // ---- stage misc + x/W_in (into reg2; used once) ----
    float* xsL  = reg2;          // 810
    float* winL = reg2 + 810;    // 1280
    for (int i = t; i < NN + 1; i += 1024) goffL[i] = goff_g[i];
    for (int i = t; i < EE; i += 1024) gsendL[i] = (unsigned short)gsend_g[i];
    if (t < 512) { baseL[t] = basev[t]; extL[t] = extv[t]; }
    if (t < 128) bm1L[t] = b_m1[t];
    for (int i = t; i < NN * 10; i += 1024) xsL[i] = x[(long)b * (NN * 10) + i];
    for (int i = t; i < HH * 10; i += 1024) winL[i] = W_in[i];
    __syncthreads();

    // ---- input projection: hRM[r][m] ----
    for (int idx = t; idx < NN * HH; idx += 1024) {
        int r = idx >> 7, m = idx & 127;
        float acc = b_in[m];
#pragma unroll
        for (int k = 0; k < 10; k++) acc += xsL[r * 10 + k] * winL[m * 10 + k];
        hRM[r * HSTR + m] = acc;
    }
    __syncthreads();

    // ======================= 8 message-passing steps =======================
    for (int step = 0; step < NSTEPS; step++) {
        float ghr[11], ghz[11], ghn[11];
        // ---------- fused pass over h: hAB cols {c,128+c} + gh gates ----------
        {
            float accA[11], accB[11];
#pragma unroll
            for (int i = 0; i < 11; i++) {
                accA[i] = 0.f; accB[i] = 0.f;
                ghr[i] = 0.f; ghz[i] = 0.f; ghn[i] = 0.f;
            }
            for (int kc = 0; kc < 128; kc += 4) {
                const int q4 = kc >> 2;
                f32x4 bA = *(const f32x4*)(W1q + (q4 * 256 + c) * 4);
                f32x4 bB = *(const f32x4*)(W1q + (q4 * 256 + 128 + c) * 4);
                const int g4 = (128 + kc) >> 2;
                f32x4 bR = *(const f32x4*)(Wgq + (g4 * G3 + c) * 4);
                f32x4 bZ = *(const f32x4*)(Wgq + (g4 * G3 + 128 + c) * 4);
                f32x4 bN = *(const f32x4*)(Wgq + (g4 * G3 + 256 + c) * 4);
#pragma unroll
                for (int i = 0; i < 11; i++) {
                    if (i < nR) {
                        f32x4 a = *(const f32x4*)(hRM + (rowBase + i) * HSTR + kc);
#pragma unroll
                        for (int j = 0; j < 4; j++) {
                            accA[i] = fmaf(a[j], bA[j], accA[i]);
                            accB[i] = fmaf(a[j], bB[j], accB[i]);
                            ghr[i]  = fmaf(a[j], bR[j], ghr[i]);
                            ghz[i]  = fmaf(a[j], bZ[j], ghz[i]);
                            ghn[i]  = fmaf(a[j], bN[j], ghn[i]);
                        }
                    }
                }
            }
            float* hAB = reg2;
#pragma unroll
            for (int i = 0; i < 11; i++) {
                if (i < nR) {
                    int row = rowBase + i;
                    hAB[row * ABSTR + c] = accA[i];
                    hAB[row * ABSTR + 128 + c] = accB[i];
                }
            }
        }
        __syncthreads();   // B1: hAB ready

        // ---------- edge aggregation (feature quad fq per lane) ----------
        float sv[3][4];
        {
            float bq[4];
#pragma unroll
            for (int j = 0; j < 4; j++) bq[j] = bm1L[fq + j];
#pragma unroll
            for (int s = 0; s < 3; s++) {
                int row = rW + 32 * s;
                if (row >= NN) { sv[s][0] = sv[s][1] = sv[s][2] = sv[s][3] = 0.f; continue; }
                int e0 = goffL[row], e1 = goffL[row + 1];
                f32x4 hb = *(const f32x4*)(reg2 + row * ABSTR + 128 + fq);
                float hbb[4], ac[4];
#pragma unroll
                for (int j = 0; j < 4; j++) { hbb[j] = hb[j] + bq[j]; ac[j] = 0.f; }
                for (int e = e0; e < e1; e++) {
                    int sn = gsendL[e];
                    f32x4 av = *(const f32x4*)(reg2 + sn * ABSTR + fq);
#pragma unroll
                    for (int j = 0; j < 4; j++) ac[j] += fmaxf(av[j] + hbb[j], 0.f);
                }
#pragma unroll
                for (int j = 0; j < 4; j++) sv[s][j] = ac[j];
            }
        }
        __syncthreads();   // B2: hAB reads done, reg2 reusable as smRM
        {
#pragma unroll
            for (int s = 0; s < 3; s++) {
                int row = rW + 32 * s;
                if (row >= NN) continue;
                f32x4 svv = {sv[s][0], sv[s][1], sv[s][2], sv[s][3]};
                *(f32x4*)(reg2 + row * HSTR + fq) = svv;
            }
        }
        __syncthreads();   // B3: smRM ready

        // ---------- gi pass: A = sm, B rows 0..127 -> rr, zz, ni ----------
        {
            float rr[11], zz[11], ni[11];
#pragma unroll
            for (int i = 0; i < 11; i++) { rr[i] = 0.f; zz[i] = 0.f; ni[i] = 0.f; }
            const float* smRM = reg2;
            for (int kc = 0; kc < 128; kc += 4) {
                const int g4 = kc >> 2;
                f32x4 bR = *(const f32x4*)(Wgq + (g4 * G3 + c) * 4);
                f32x4 bZ = *(const f32x4*)(Wgq + (g4 * G3 + 128 + c) * 4);
                f32x4 bN = *(const f32x4*)(Wgq + (g4 * G3 + 256 + c) * 4);
#pragma unroll
                for (int i = 0; i < 11; i++) {
                    if (i < nR) {
                        f32x4 a = *(const f32x4*)(smRM + (rowBase + i) * HSTR + kc);
#pragma unroll
                        for (int j = 0; j < 4; j++) {
                            rr[i] = fmaf(a[j], bR[j], rr[i]);
                            zz[i] = fmaf(a[j], bZ[j], zz[i]);
                            ni[i] = fmaf(a[j], bN[j], ni[i]);
                        }
                    }
                }
            }

            // ---- GRU epilogue: thread updates h[row][c] (disjoint ownership) ----
            const float base0 = baseL[c],       ext0 = extL[c];
            const float base1 = baseL[128 + c], ext1 = extL[128 + c];
            const float base2 = baseL[256 + c], ext2 = extL[256 + c];
            const float base3 = baseL[384 + c];
#pragma unroll
            for (int i = 0; i < 11; i++) {
                if (i < nR) {
                    int row = rowBase + i;
                    float cf = (float)(goffL[row + 1] - goffL[row]);
                    float g0 = rr[i] + ghr[i] + base0 + cf * ext0;
                    float g1 = zz[i] + ghz[i] + base1 + cf * ext1;
                    float g2 = ni[i] + base2 + cf * ext2;
                    float g3 = ghn[i] + base3;
                    float rg_ = 1.f / (1.f + __expf(-g0));
                    float z   = 1.f / (1.f + __expf(-g1));
                    float npre = g2 + rg_ * g3;
                    float ax = fabsf(npre);
                    float e  = __expf(-2.f * ax);
                    float tt = (1.f - e) / (1.f + e);
                    float n  = copysignf(tt, npre);
                    float ho = hRM[row * HSTR + c];
                    hRM[row * HSTR + c] = (1.f - z) * n + z * ho;
                }
            }
        }
        __syncthreads();   // B4: smRM reads done + new h visible
    }

    // ======================= output head =======================
    // hid = relu(h @ W_o1^T + b_o1): thread (g,c) -> col c, its rows
    {
        float acc3[11];
#pragma unroll
        for (int i = 0; i < 11; i++) acc3[i] = 0.f;
        for (int kc = 0; kc < 128; kc += 4) {
            f32x4 bb = *(const f32x4*)(Wo1q + ((kc >> 2) * 128 + c) * 4);
#pragma unroll
            for (int i = 0; i < 11; i++) {
                if (i < nR) {
                    f32x4 a = *(const f32x4*)(hRM + (rowBase + i) * HSTR + kc);
#pragma unroll
                    for (int j = 0; j < 4; j++) acc3[i] = fmaf(a[j], bb[j], acc3[i]);
                }
            }
        }
        float bo = b_o1[c];
        __syncthreads();   // hRM reads done; reg2 -> hid
#pragma unroll
        for (int i = 0; i < 11; i++) {
            if (i < nR) {
                int row = rowBase + i;
                reg2[row * HSTR + c] = fmaxf(acc3[i] + bo, 0.f);
            }
        }
    }
    __syncthreads();
    // stage W_o2/b_o2 into hRM area (dead)
    {
        float* wo2L = hRM;
        float* bo2L = hRM + 1152;
        for (int i = t; i < 9 * HH; i += 1024) wo2L[i] = W_o2[i];
        if (t < 9) bo2L[t] = b_o2[t];
    }
    __syncthreads();
    {
        const float* wo2L = hRM;
        const float* bo2L = hRM + 1152;
        for (int idx = t; idx < NN * 9; idx += 1024) {
            int r = idx / 9, qq = idx - 9 * r;
            float acc = bo2L[qq];
            const float* hrow = reg2 + r * HSTR;
            const float* wrow = wo2L + qq * HH;
            for (int k = 0; k < HH; k++) acc = fmaf(hrow[k], wrow[k], acc);
            out[((long)b * NN + r) * 9 + qq] = acc;
        }
    }
}

// ---------------------------------------------------------------------------
extern "C" void kernel_launch(void* const* d_in, const int* in_sizes, int n_in,
                              void* d_out, int out_size, void* d_ws, size_t ws_size,
                              hipStream_t stream) {
    const float* x      = (const float*)d_in[0];
    const int* ei       = (const int*)d_in[1];
    const float* W_in   = (const float*)d_in[2];
    const float* b_in   = (const float*)d_in[3];
    const float* W_m1   = (const float*)d_in[4];
    const float* b_m1   = (const float*)d_in[5];
    const float* W_m2   = (const float*)d_in[6];
    const float* b_m2   = (const float*)d_in[7];
    const float* W_ih   = (const float*)d_in[8];
    const float* W_hh   = (const float*)d_in[9];
    const float* b_ih   = (const float*)d_in[10];
    const float* b_hh   = (const float*)d_in[11];
    const float* W_o1   = (const float*)d_in[12];
    const float* b_o1   = (const float*)d_in[13];
    const float* W_o2   = (const float*)d_in[14];
    const float* b_o2   = (const float*)d_in[15];
    float* out = (float*)d_out;

    char* ws = (char*)d_ws;
    size_t off = 0;
    auto alloc = [&](size_t bytes) -> char* {
        char* p = ws + off;
        off += (bytes + 255) & ~(size_t)255;
        return p;
    };
    float* Wc    = (float*)alloc((size_t)G3 * HH * 4);
    float* W1q   = (float*)alloc(128 * 256 * 4);
    float* Wgq   = (float*)alloc(256 * G3 * 4);
    float* Wo1q  = (float*)alloc(128 * 128 * 4);
    float* basev = (float*)alloc(512 * 4);
    float* extv  = (float*)alloc(512 * 4);
    int* goff    = (int*)alloc((NN + 1) * 4);
    int* gsend   = (int*)alloc(EE * 4);

    prep_graph<<<1, 128, 0, stream>>>(ei, goff, gsend);
    prep_wc<<<(G3 * HH + 255) / 256, 256, 0, stream>>>(W_ih, W_m2, Wc);
    prep_bias<<<2, 256, 0, stream>>>(W_ih, b_m2, b_ih, b_hh, basev, extv);
    prep_w1q<<<128, 256, 0, stream>>>(W_m1, W1q);
    prep_wgq<<<(256 * G3 + 255) / 256, 256, 0, stream>>>(Wc, W_hh, Wgq);
    prep_wo1q<<<64, 256, 0, stream>>>(W_o1, Wo1q);

    (void)hipFuncSetAttribute((const void*)fused_rrn,
                              hipFuncAttributeMaxDynamicSharedMemorySize,
                              (int)LDS_BYTES);
    fused_rrn<<<BB, 1024, LDS_BYTES, stream>>>(
        x, W_in, b_in, b_m1, W1q, Wgq, basev, extv,
        Wo1q, b_o1, W_o2, b_o2, goff, gsend, out);
}

// Round 10
// 3924.388 us; speedup vs baseline: 1.4374x; 1.3961x over previous
//
#include <hip/hip_runtime.h>

#define BB 1024
#define NN 81
#define EE 1620
#define HH 128
#define G3 384
#define NSTEPS 8

#define HSTR 132     // hRM/smRM/hid row stride (floats)
#define ABSTR 260    // hAB row stride (floats)

typedef __attribute__((ext_vector_type(4))) float f32x4;

// ---- LDS float offsets ----
#define F_H     0            // hRM 81 x 132 = 10692
#define F_R2    10692        // 21060: union{ xs+win | hAB 81x260 | smRM 81x132 | hid 81x132 }
#define F_GOFF  31752        // 82 ints
#define F_GSEND 31834        // 1620 ushorts (810 float slots)
#define F_BM1   32644        // 128
#define F_BASE  32772        // 512
#define F_EXT   33284        // 512
#define F_TOT   33796
#define LDS_BYTES (F_TOT * 4)   // 135184 bytes

// ---------------------------------------------------------------------------
// prep_graph: CSR by receiver (int32 edge input) — verified R2/R4-R9.
// ---------------------------------------------------------------------------
__global__ __launch_bounds__(128) void prep_graph(const int* __restrict__ ei,
                                                  int* __restrict__ goff,
                                                  int* __restrict__ gsend) {
    __shared__ int eis[2 * EE];
    __shared__ int cs[NN];
    __shared__ int offs[NN + 1];
    int tid = threadIdx.x;
    for (int i = tid; i < 2 * EE; i += 128) eis[i] = ei[i];
    __syncthreads();
    if (tid < NN) {
        int c = 0;
        for (int e = 0; e < EE; e++) if (eis[EE + e] == tid) c++;
        cs[tid] = c;
    }
    __syncthreads();
    if (tid == 0) {
        int o = 0;
        for (int r = 0; r < NN; r++) { offs[r] = o; o += cs[r]; }
        offs[NN] = o;
    }
    __syncthreads();
    if (tid < NN) {
        int pos = offs[tid];
        for (int e = 0; e < EE; e++) {
            if (eis[EE + e] == tid) gsend[pos++] = eis[e];
        }
        goff[tid] = offs[tid];
    }
    if (tid == 0) goff[NN] = offs[NN];
}

// ---------------------------------------------------------------------------
// prep_wc: Wc[c][o] = sum_m W_ih[c][m] * W_m2[m][o]   (384 x 128)
// ---------------------------------------------------------------------------
__global__ __launch_bounds__(256) void prep_wc(const float* __restrict__ W_ih,
                                               const float* __restrict__ W_m2,
                                               float* __restrict__ Wc) {
    int idx = blockIdx.x * 256 + threadIdx.x;
    if (idx >= G3 * HH) return;
    int c = idx >> 7, o = idx & 127;
    float acc = 0.f;
    for (int m = 0; m < HH; m++) acc += W_ih[c * HH + m] * W_m2[m * HH + o];
    Wc[idx] = acc;
}

// ---------------------------------------------------------------------------
// prep_bias: base[512], ext[512]
// ---------------------------------------------------------------------------
__global__ __launch_bounds__(256) void prep_bias(const float* __restrict__ W_ih,
                                                 const float* __restrict__ b_m2,
                                                 const float* __restrict__ b_ih,
                                                 const float* __restrict__ b_hh,
                                                 float* __restrict__ basev,
                                                 float* __restrict__ extv) {
    int c = blockIdx.x * 256 + threadIdx.x;
    if (c >= 512) return;
    float base, ext;
    if (c < 384) {
        float bwc = 0.f;
        for (int m = 0; m < HH; m++) bwc += W_ih[c * HH + m] * b_m2[m];
        ext = bwc;
        base = (c < 256) ? (b_ih[c] + b_hh[c]) : b_ih[c];
    } else {
        ext = 0.f;
        base = b_hh[c - 128];
    }
    basev[c] = base;
    extv[c] = ext;
}

// ---------------------------------------------------------------------------
// prep_w1q: quad-packed W1: W1q[((k>>2)*256 + c)*4 + (k&3)] = W1[c][k]
// ---------------------------------------------------------------------------
__global__ __launch_bounds__(256) void prep_w1q(const float* __restrict__ W_m1,
                                                float* __restrict__ W1q) {
    int idx = blockIdx.x * 256 + threadIdx.x;   // 128*256
    if (idx >= 128 * 256) return;
    int k = idx >> 8, c = idx & 255;
    float v = (c < 128) ? W_m1[c * 256 + k] : W_m1[(c - 128) * 256 + 128 + k];
    W1q[((k >> 2) * 256 + c) * 4 + (k & 3)] = v;
}

// ---------------------------------------------------------------------------
// prep_wgq: quad-packed gates: Wgq[((k>>2)*384 + c)*4 + (k&3)]
//   = k<128 ? Wc[c][k] : W_hh[c][k-128]      (k in [0,256))
// ---------------------------------------------------------------------------
__global__ __launch_bounds__(256) void prep_wgq(const float* __restrict__ Wc,
                                                const float* __restrict__ W_hh,
                                                float* __restrict__ Wgq) {
    int idx = blockIdx.x * 256 + threadIdx.x;   // 256*384
    if (idx >= 256 * G3) return;
    int k = idx / G3;
    int c = idx - k * G3;
    float v = (k < 128) ? Wc[c * HH + k] : W_hh[c * HH + (k - 128)];
    Wgq[((k >> 2) * G3 + c) * 4 + (k & 3)] = v;
}

// ---------------------------------------------------------------------------
// prep_wo1q: Wo1q[((k>>2)*128 + c)*4 + (k&3)] = W_o1[c][k]
// ---------------------------------------------------------------------------
__global__ __launch_bounds__(256) void prep_wo1q(const float* __restrict__ W_o1,
                                                 float* __restrict__ Wo1q) {
    int idx = blockIdx.x * 256 + threadIdx.x;
    if (idx >= 128 * 128) return;
    int k = idx >> 7, c = idx & 127;
    Wo1q[((k >> 2) * 128 + c) * 4 + (k & 3)] = W_o1[c * HH + k];
}

// ---------------------------------------------------------------------------
// fused_rrn: one workgroup per puzzle, 512 threads (8 waves), fp32.
// __launch_bounds__(512, 2): the ONLY config that demonstrably gets 128 VGPRs
// (R4). 1024-thread builds pin VGPR=64 and spill (R7-R9: up to 2.4GB scratch).
// Map: thread (g = t>>7 in 0..3, c = t&127) owns rows [20g, 20g+nR) for gate
// cols {c,128+c,256+c}. GEMM2 split into 3 low-pressure passes (peak live
// ~85 regs): pass1 rr/zz(sm,h) -> rg_,z ; pass2a nh(h) -> tmp=rg_*(nh+b3) ;
// pass2b ni(sm) -> epilogue. Same k-ascending order as R7 => bit-identical.
// ---------------------------------------------------------------------------
__global__ __launch_bounds__(512, 2) void fused_rrn(
    const float* __restrict__ x,
    const float* __restrict__ W_in, const float* __restrict__ b_in,
    const float* __restrict__ b_m1,
    const float* __restrict__ W1q, const float* __restrict__ Wgq,
    const float* __restrict__ basev, const float* __restrict__ extv,
    const float* __restrict__ Wo1q, const float* __restrict__ b_o1,
    const float* __restrict__ W_o2, const float* __restrict__ b_o2,
    const int* __restrict__ goff_g, const int* __restrict__ gsend_g,
    float* __restrict__ out)
{
    extern __shared__ float smf[];
    float* hRM  = smf + F_H;
    float* reg2 = smf + F_R2;
    int*   goffL = (int*)(smf + F_GOFF);
    unsigned short* gsendL = (unsigned short*)(smf + F_GSEND);
    float* bm1L  = smf + F_BM1;
    float* baseL = smf + F_BASE;
    float* extL  = smf + F_EXT;

    const int t  = threadIdx.x;
    const int b  = blockIdx.x;
    const int c  = t & 127;           // gate column
    const int g  = t >> 7;            // row group 0..3
    const int rowBase = g * 20;
    const int nR = (g == 3) ? 21 : 20;
    const int rW = t & 31;            // edge-phase row lane
    const int f8 = 8 * (t >> 5);      // edge-phase feature octet (0..120)

    // ---- stage misc + x/W_in (into reg2; used once) ----
    float* xsL  = reg2;          // 810
    float* winL = reg2 + 810;    // 1280
    for (int i = t; i < NN + 1; i += 512) goffL[i] = goff_g[i];
    for (int i = t; i < EE; i += 512) gsendL[i] = (unsigned short)gsend_g[i];
    baseL[t] = basev[t];
    extL[t]  = extv[t];
    if (t < 128) bm1L[t] = b_m1[t];
    for (int i = t; i < NN * 10; i += 512) xsL[i] = x[(long)b * (NN * 10) + i];
    for (int i = t; i < HH * 10; i += 512) winL[i] = W_in[i];
    __syncthreads();

    // ---- input projection: hRM[r][m] ----
    for (int idx = t; idx < NN * HH; idx += 512) {
        int r = idx >> 7, m = idx & 127;
        float acc = b_in[m];
#pragma unroll
        for (int k = 0; k < 10; k++) acc += xsL[r * 10 + k] * winL[m * 10 + k];
        hRM[r * HSTR + m] = acc;
    }
    __syncthreads();

    // ======================= 8 message-passing steps =======================
    for (int step = 0; step < NSTEPS; step++) {
        // ---------- GEMM1: hAB = h @ W1^T (cols c, 128+c) ----------
        {
            float accA[21], accB[21];
#pragma unroll
            for (int i = 0; i < 21; i++) { accA[i] = 0.f; accB[i] = 0.f; }
            for (int kc = 0; kc < 128; kc += 4) {
                const int q4 = kc >> 2;
                f32x4 bA = *(const f32x4*)(W1q + (q4 * 256 + c) * 4);
                f32x4 bB = *(const f32x4*)(W1q + (q4 * 256 + 128 + c) * 4);
#pragma unroll
                for (int i = 0; i < 21; i++) {
                    if (i < nR) {
                        f32x4 a = *(const f32x4*)(hRM + (rowBase + i) * HSTR + kc);
#pragma unroll
                        for (int j = 0; j < 4; j++) {
                            accA[i] = fmaf(a[j], bA[j], accA[i]);
                            accB[i] = fmaf(a[j], bB[j], accB[i]);
                        }
                    }
                }
            }
            float* hAB = reg2;
#pragma unroll
            for (int i = 0; i < 21; i++) {
                if (i < nR) {
                    int row = rowBase + i;
                    hAB[row * ABSTR + c] = accA[i];
                    hAB[row * ABSTR + 128 + c] = accB[i];
                }
            }
        }
        __syncthreads();   // B1: hAB ready

        // ---------- edge aggregation: 3 rows x 8 features per thread ----------
        float sv[3][8];
        {
            float bq[8];
#pragma unroll
            for (int j = 0; j < 8; j++) bq[j] = bm1L[f8 + j];
#pragma unroll
            for (int s = 0; s < 3; s++) {
                int row = rW + 32 * s;
                if (row >= NN) {
#pragma unroll
                    for (int j = 0; j < 8; j++) sv[s][j] = 0.f;
                    continue;
                }
                int e0 = goffL[row], e1 = goffL[row + 1];
                f32x4 hb0 = *(const f32x4*)(reg2 + row * ABSTR + 128 + f8);
                f32x4 hb1 = *(const f32x4*)(reg2 + row * ABSTR + 128 + f8 + 4);
                float hbb[8], ac[8];
#pragma unroll
                for (int j = 0; j < 4; j++) {
                    hbb[j] = hb0[j] + bq[j];
                    hbb[4 + j] = hb1[j] + bq[4 + j];
                    ac[j] = 0.f; ac[4 + j] = 0.f;
                }
                for (int e = e0; e < e1; e++) {
                    int sn = gsendL[e];
                    f32x4 av0 = *(const f32x4*)(reg2 + sn * ABSTR + f8);
                    f32x4 av1 = *(const f32x4*)(reg2 + sn * ABSTR + f8 + 4);
#pragma unroll
                    for (int j = 0; j < 4; j++) {
                        ac[j]     += fmaxf(av0[j] + hbb[j], 0.f);
                        ac[4 + j] += fmaxf(av1[j] + hbb[4 + j], 0.f);
                    }
                }
#pragma unroll
                for (int j = 0; j < 8; j++) sv[s][j] = ac[j];
            }
        }
        __syncthreads();   // B2: hAB reads done, reg2 reusable as smRM
        {
#pragma unroll
            for (int s = 0; s < 3; s++) {
                int row = rW + 32 * s;
                if (row >= NN) continue;
                f32x4 v0 = {sv[s][0], sv[s][1], sv[s][2], sv[s][3]};
                f32x4 v1 = {sv[s][4], sv[s][5], sv[s][6], sv[s][7]};
                *(f32x4*)(reg2 + row * HSTR + f8) = v0;
                *(f32x4*)(reg2 + row * HSTR + f8 + 4) = v1;
            }
        }
        __syncthreads();   // B3: smRM ready

        // ---------- GEMM2 split passes ----------
        {
            const float* smRM = reg2;
            float rg_[21], z[21];
            // ---- pass1: rr, zz over sm (rows 0..127) then h (rows 128..255)
            {
                float rr[21], zz[21];
#pragma unroll
                for (int i = 0; i < 21; i++) { rr[i] = 0.f; zz[i] = 0.f; }
                for (int kc = 0; kc < 128; kc += 4) {
                    const int g4 = kc >> 2;
                    f32x4 bR = *(const f32x4*)(Wgq + (g4 * G3 + c) * 4);
                    f32x4 bZ = *(const f32x4*)(Wgq + (g4 * G3 + 128 + c) * 4);
#pragma unroll
                    for (int i = 0; i < 21; i++) {
                        if (i < nR) {
                            f32x4 a = *(const f32x4*)(smRM + (rowBase + i) * HSTR + kc);
#pragma unroll
                            for (int j = 0; j < 4; j++) {
                                rr[i] = fmaf(a[j], bR[j], rr[i]);
                                zz[i] = fmaf(a[j], bZ[j], zz[i]);
                            }
                        }
                    }
                }
                for (int kc = 0; kc < 128; kc += 4) {
                    const int g4 = (128 + kc) >> 2;
                    f32x4 bR = *(const f32x4*)(Wgq + (g4 * G3 + c) * 4);
                    f32x4 bZ = *(const f32x4*)(Wgq + (g4 * G3 + 128 + c) * 4);
#pragma unroll
                    for (int i = 0; i < 21; i++) {
                        if (i < nR) {
                            f32x4 a = *(const f32x4*)(hRM + (rowBase + i) * HSTR + kc);
#pragma unroll
                            for (int j = 0; j < 4; j++) {
                                rr[i] = fmaf(a[j], bR[j], rr[i]);
                                zz[i] = fmaf(a[j], bZ[j], zz[i]);
                            }
                        }
                    }
                }
                const float base0 = baseL[c],       ext0 = extL[c];
                const float base1 = baseL[128 + c], ext1 = extL[128 + c];
#pragma unroll
                for (int i = 0; i < 21; i++) {
                    if (i < nR) {
                        int row = rowBase + i;
                        float cf = (float)(goffL[row + 1] - goffL[row]);
                        float g0 = rr[i] + base0 + cf * ext0;
                        float g1 = zz[i] + base1 + cf * ext1;
                        rg_[i] = 1.f / (1.f + __expf(-g0));
                        z[i]   = 1.f / (1.f + __expf(-g1));
                    }
                }
            }
            // ---- pass2a: nh over h -> tmp = rg_ * (nh + base3)
            float tmp[21];
            {
                float nh[21];
#pragma unroll
                for (int i = 0; i < 21; i++) nh[i] = 0.f;
                for (int kc = 0; kc < 128; kc += 4) {
                    const int g4 = (128 + kc) >> 2;
                    f32x4 bN = *(const f32x4*)(Wgq + (g4 * G3 + 256 + c) * 4);
#pragma unroll
                    for (int i = 0; i < 21; i++) {
                        if (i < nR) {
                            f32x4 a = *(const f32x4*)(hRM + (rowBase + i) * HSTR + kc);
#pragma unroll
                            for (int j = 0; j < 4; j++) nh[i] = fmaf(a[j], bN[j], nh[i]);
                        }
                    }
                }
                const float base3 = baseL[384 + c];
#pragma unroll
                for (int i = 0; i < 21; i++) {
                    if (i < nR) tmp[i] = rg_[i] * (nh[i] + base3);
                }
            }
            // ---- pass2b: ni over sm -> GRU epilogue
            {
                float ni[21];
#pragma unroll
                for (int i = 0; i < 21; i++) ni[i] = 0.f;
                for (int kc = 0; kc < 128; kc += 4) {
                    const int g4 = kc >> 2;
                    f32x4 bN = *(const f32x4*)(Wgq + (g4 * G3 + 256 + c) * 4);
#pragma unroll
                    for (int i = 0; i < 21; i++) {
                        if (i < nR) {
                            f32x4 a = *(const f32x4*)(smRM + (rowBase + i) * HSTR + kc);
#pragma unroll
                            for (int j = 0; j < 4; j++) ni[i] = fmaf(a[j], bN[j], ni[i]);
                        }
                    }
                }
                __syncthreads();   // B4: all smRM/hRM reads done before h writes

                const float base2 = baseL[256 + c], ext2 = extL[256 + c];
#pragma unroll
                for (int i = 0; i < 21; i++) {
                    if (i < nR) {
                        int row = rowBase + i;
                        float cf = (float)(goffL[row + 1] - goffL[row]);
                        float npre = ni[i] + base2 + cf * ext2 + tmp[i];
                        float ax = fabsf(npre);
                        float e  = __expf(-2.f * ax);
                        float tt = (1.f - e) / (1.f + e);
                        float n  = copysignf(tt, npre);
                        float ho = hRM[row * HSTR + c];
                        hRM[row * HSTR + c] = (1.f - z[i]) * n + z[i] * ho;
                    }
                }
            }
        }
        __syncthreads();   // B5: new h visible
    }

    // ======================= output head =======================
    // hid = relu(h @ W_o1^T + b_o1): thread (g,c) -> col c, its rows
    {
        float acc3[21];
#pragma unroll
        for (int i = 0; i < 21; i++) acc3[i] = 0.f;
        for (int kc = 0; kc < 128; kc += 4) {
            f32x4 bb = *(const f32x4*)(Wo1q + ((kc >> 2) * 128 + c) * 4);
#pragma unroll
            for (int i = 0; i < 21; i++) {
                if (i < nR) {
                    f32x4 a = *(const f32x4*)(hRM + (rowBase + i) * HSTR + kc);
#pragma unroll
                    for (int j = 0; j < 4; j++) acc3[i] = fmaf(a[j], bb[j], acc3[i]);
                }
            }
        }
        float bo = b_o1[c];
        __syncthreads();   // hRM reads done; reg2 -> hid
#pragma unroll
        for (int i = 0; i < 21; i++) {
            if (i < nR) {
                int row = rowBase + i;
                reg2[row * HSTR + c] = fmaxf(acc3[i] + bo, 0.f);
            }
        }
    }
    __syncthreads();
    // stage W_o2/b_o2 into hRM area (dead)
    {
        float* wo2L = hRM;
        float* bo2L = hRM + 1152;
        for (int i = t; i < 9 * HH; i += 512) wo2L[i] = W_o2[i];
        if (t < 9) bo2L[t] = b_o2[t];
    }
    __syncthreads();
    {
        const float* wo2L = hRM;
        const float* bo2L = hRM + 1152;
        for (int idx = t; idx < NN * 9; idx += 512) {
            int r = idx / 9, qq = idx - 9 * r;
            float acc = bo2L[qq];
            const float* hrow = reg2 + r * HSTR;
            const float* wrow = wo2L + qq * HH;
            for (int k = 0; k < HH; k++) acc = fmaf(hrow[k], wrow[k], acc);
            out[((long)b * NN + r) * 9 + qq] = acc;
        }
    }
}

// ---------------------------------------------------------------------------
extern "C" void kernel_launch(void* const* d_in, const int* in_sizes, int n_in,
                              void* d_out, int out_size, void* d_ws, size_t ws_size,
                              hipStream_t stream) {
    const float* x      = (const float*)d_in[0];
    const int* ei       = (const int*)d_in[1];
    const float* W_in   = (const float*)d_in[2];
    const float* b_in   = (const float*)d_in[3];
    const float* W_m1   = (const float*)d_in[4];
    const float* b_m1   = (const float*)d_in[5];
    const float* W_m2   = (const float*)d_in[6];
    const float* b_m2   = (const float*)d_in[7];
    const float* W_ih   = (const float*)d_in[8];
    const float* W_hh   = (const float*)d_in[9];
    const float* b_ih   = (const float*)d_in[10];
    const float* b_hh   = (const float*)d_in[11];
    const float* W_o1   = (const float*)d_in[12];
    const float* b_o1   = (const float*)d_in[13];
    const float* W_o2   = (const float*)d_in[14];
    const float* b_o2   = (const float*)d_in[15];
    float* out = (float*)d_out;

    char* ws = (char*)d_ws;
    size_t off = 0;
    auto alloc = [&](size_t bytes) -> char* {
        char* p = ws + off;
        off += (bytes + 255) & ~(size_t)255;
        return p;
    };
    float* Wc    = (float*)alloc((size_t)G3 * HH * 4);
    float* W1q   = (float*)alloc(128 * 256 * 4);
    float* Wgq   = (float*)alloc(256 * G3 * 4);
    float* Wo1q  = (float*)alloc(128 * 128 * 4);
    float* basev = (float*)alloc(512 * 4);
    float* extv  = (float*)alloc(512 * 4);
    int* goff    = (int*)alloc((NN + 1) * 4);
    int* gsend   = (int*)alloc(EE * 4);

    prep_graph<<<1, 128, 0, stream>>>(ei, goff, gsend);
    prep_wc<<<(G3 * HH + 255) / 256, 256, 0, stream>>>(W_ih, W_m2, Wc);
    prep_bias<<<2, 256, 0, stream>>>(W_ih, b_m2, b_ih, b_hh, basev, extv);
    prep_w1q<<<128, 256, 0, stream>>>(W_m1, W1q);
    prep_wgq<<<(256 * G3 + 255) / 256, 256, 0, stream>>>(Wc, W_hh, Wgq);
    prep_wo1q<<<64, 256, 0, stream>>>(W_o1, Wo1q);

    (void)hipFuncSetAttribute((const void*)fused_rrn,
                              hipFuncAttributeMaxDynamicSharedMemorySize,
                              (int)LDS_BYTES);
    fused_rrn<<<BB, 512, LDS_BYTES, stream>>>(
        x, W_in, b_in, b_m1, W1q, Wgq, basev, extv,
        Wo1q, b_o1, W_o2, b_o2, goff, gsend, out);
}

// Round 11
// 3425.251 us; speedup vs baseline: 1.6469x; 1.1457x over previous
//
#include <hip/hip_runtime.h>

#define BB 1024
#define NN 81
#define EE 1620
#define HH 128
#define G3 384
#define NSTEPS 8

#define HSTR 132     // hRM/smRM/hid row stride (floats)
#define ABSTR 260    // hAB row stride (floats)

typedef __attribute__((ext_vector_type(4))) float f32x4;

// ---- LDS float offsets ----
#define F_H     0            // hRM 81 x 132 = 10692
#define F_R2    10692        // 21060: union{ xs+win | hAB 81x260 | smRM 81x132 | hid 81x132 }
#define F_GOFF  31752        // 82 ints
#define F_GSEND 31834        // 1620 ushorts (810 float slots)
#define F_BM1   32644        // 128
#define F_BASE  32772        // 512
#define F_EXT   33284        // 512
#define F_TOT   33796
#define LDS_BYTES (F_TOT * 4)   // 135184 bytes

// ---------------------------------------------------------------------------
// prep_graph: CSR by receiver (int32 edge input) — verified R2/R4-R10.
// ---------------------------------------------------------------------------
__global__ __launch_bounds__(128) void prep_graph(const int* __restrict__ ei,
                                                  int* __restrict__ goff,
                                                  int* __restrict__ gsend) {
    __shared__ int eis[2 * EE];
    __shared__ int cs[NN];
    __shared__ int offs[NN + 1];
    int tid = threadIdx.x;
    for (int i = tid; i < 2 * EE; i += 128) eis[i] = ei[i];
    __syncthreads();
    if (tid < NN) {
        int c = 0;
        for (int e = 0; e < EE; e++) if (eis[EE + e] == tid) c++;
        cs[tid] = c;
    }
    __syncthreads();
    if (tid == 0) {
        int o = 0;
        for (int r = 0; r < NN; r++) { offs[r] = o; o += cs[r]; }
        offs[NN] = o;
    }
    __syncthreads();
    if (tid < NN) {
        int pos = offs[tid];
        for (int e = 0; e < EE; e++) {
            if (eis[EE + e] == tid) gsend[pos++] = eis[e];
        }
        goff[tid] = offs[tid];
    }
    if (tid == 0) goff[NN] = offs[NN];
}

// ---------------------------------------------------------------------------
// prep_wc: Wc[c][o] = sum_m W_ih[c][m] * W_m2[m][o]   (384 x 128)
// ---------------------------------------------------------------------------
__global__ __launch_bounds__(256) void prep_wc(const float* __restrict__ W_ih,
                                               const float* __restrict__ W_m2,
                                               float* __restrict__ Wc) {
    int idx = blockIdx.x * 256 + threadIdx.x;
    if (idx >= G3 * HH) return;
    int c = idx >> 7, o = idx & 127;
    float acc = 0.f;
    for (int m = 0; m < HH; m++) acc += W_ih[c * HH + m] * W_m2[m * HH + o];
    Wc[idx] = acc;
}

// ---------------------------------------------------------------------------
// prep_bias: base[512], ext[512]
// ---------------------------------------------------------------------------
__global__ __launch_bounds__(256) void prep_bias(const float* __restrict__ W_ih,
                                                 const float* __restrict__ b_m2,
                                                 const float* __restrict__ b_ih,
                                                 const float* __restrict__ b_hh,
                                                 float* __restrict__ basev,
                                                 float* __restrict__ extv) {
    int c = blockIdx.x * 256 + threadIdx.x;
    if (c >= 512) return;
    float base, ext;
    if (c < 384) {
        float bwc = 0.f;
        for (int m = 0; m < HH; m++) bwc += W_ih[c * HH + m] * b_m2[m];
        ext = bwc;
        base = (c < 256) ? (b_ih[c] + b_hh[c]) : b_ih[c];
    } else {
        ext = 0.f;
        base = b_hh[c - 128];
    }
    basev[c] = base;
    extv[c] = ext;
}

// ---------------------------------------------------------------------------
// prep_w1q: quad-packed W1: W1q[((k>>2)*256 + c)*4 + (k&3)] = W1[c][k]
// ---------------------------------------------------------------------------
__global__ __launch_bounds__(256) void prep_w1q(const float* __restrict__ W_m1,
                                                float* __restrict__ W1q) {
    int idx = blockIdx.x * 256 + threadIdx.x;   // 128*256
    if (idx >= 128 * 256) return;
    int k = idx >> 8, c = idx & 255;
    float v = (c < 128) ? W_m1[c * 256 + k] : W_m1[(c - 128) * 256 + 128 + k];
    W1q[((k >> 2) * 256 + c) * 4 + (k & 3)] = v;
}

// ---------------------------------------------------------------------------
// prep_wgq: quad-packed gates: Wgq[((k>>2)*384 + c)*4 + (k&3)]
//   = k<128 ? Wc[c][k] : W_hh[c][k-128]      (k in [0,256))
// ---------------------------------------------------------------------------
__global__ __launch_bounds__(256) void prep_wgq(const float* __restrict__ Wc,
                                                const float* __restrict__ W_hh,
                                                float* __restrict__ Wgq) {
    int idx = blockIdx.x * 256 + threadIdx.x;   // 256*384
    if (idx >= 256 * G3) return;
    int k = idx / G3;
    int c = idx - k * G3;
    float v = (k < 128) ? Wc[c * HH + k] : W_hh[c * HH + (k - 128)];
    Wgq[((k >> 2) * G3 + c) * 4 + (k & 3)] = v;
}

// ---------------------------------------------------------------------------
// prep_wo1q: Wo1q[((k>>2)*128 + c)*4 + (k&3)] = W_o1[c][k]
// ---------------------------------------------------------------------------
__global__ __launch_bounds__(256) void prep_wo1q(const float* __restrict__ W_o1,
                                                 float* __restrict__ Wo1q) {
    int idx = blockIdx.x * 256 + threadIdx.x;
    if (idx >= 128 * 128) return;
    int k = idx >> 7, c = idx & 127;
    Wo1q[((k >> 2) * 128 + c) * 4 + (k & 3)] = W_o1[c * HH + k];
}

// ---------------------------------------------------------------------------
// fused_rrn: one workgroup per puzzle, 512 threads (8 waves), fp32.
// R10 post-mortem: kernel was LDS-return-BW bound (5 sweeps x 81rows x
// 128 col-threads x 512B x 8 steps = 212 MB/block ~ 1.04ms/block ~ measured).
// R11: thread (g=t>>5 in 0..15, c32=t&31) owns 4 gate cols {c32+32j} and
// rows [5g, 5g+nR) -> each row read by 32 threads not 128: LDS 212->53 MB.
// GEMM2 keeps R10's 3-pass split (same k order => bit-identical numerics).
// ---------------------------------------------------------------------------
__global__ __launch_bounds__(512, 2) void fused_rrn(
    const float* __restrict__ x,
    const float* __restrict__ W_in, const float* __restrict__ b_in,
    const float* __restrict__ b_m1,
    const float* __restrict__ W1q, const float* __restrict__ Wgq,
    const float* __restrict__ basev, const float* __restrict__ extv,
    const float* __restrict__ Wo1q, const float* __restrict__ b_o1,
    const float* __restrict__ W_o2, const float* __restrict__ b_o2,
    const int* __restrict__ goff_g, const int* __restrict__ gsend_g,
    float* __restrict__ out)
{
    extern __shared__ float smf[];
    float* hRM  = smf + F_H;
    float* reg2 = smf + F_R2;
    int*   goffL = (int*)(smf + F_GOFF);
    unsigned short* gsendL = (unsigned short*)(smf + F_GSEND);
    float* bm1L  = smf + F_BM1;
    float* baseL = smf + F_BASE;
    float* extL  = smf + F_EXT;

    const int t   = threadIdx.x;
    const int b   = blockIdx.x;
    const int c32 = t & 31;           // base gate column (cols c32+32j, j<4)
    const int g   = t >> 5;           // row group 0..15
    const int rowBase = g * 5;
    const int nR = (g == 15) ? 6 : 5;
    const int rW = t & 31;            // edge-phase row lane
    const int f8 = 8 * (t >> 5);      // edge-phase feature octet (0..120)

    // ---- stage misc + x/W_in (into reg2; used once) ----
    float* xsL  = reg2;          // 810
    float* winL = reg2 + 810;    // 1280
    for (int i = t; i < NN + 1; i += 512) goffL[i] = goff_g[i];
    for (int i = t; i < EE; i += 512) gsendL[i] = (unsigned short)gsend_g[i];
    baseL[t] = basev[t];
    extL[t]  = extv[t];
    if (t < 128) bm1L[t] = b_m1[t];
    for (int i = t; i < NN * 10; i += 512) xsL[i] = x[(long)b * (NN * 10) + i];
    for (int i = t; i < HH * 10; i += 512) winL[i] = W_in[i];
    __syncthreads();

    // ---- input projection: hRM[r][m] ----
    for (int idx = t; idx < NN * HH; idx += 512) {
        int r = idx >> 7, m = idx & 127;
        float acc = b_in[m];
#pragma unroll
        for (int k = 0; k < 10; k++) acc += xsL[r * 10 + k] * winL[m * 10 + k];
        hRM[r * HSTR + m] = acc;
    }
    __syncthreads();

    // ======================= 8 message-passing steps =======================
    for (int step = 0; step < NSTEPS; step++) {
        // ---------- GEMM1: hAB = h @ W1^T (cols c32+32j and 128+c32+32j) ----------
        {
            float accA[6][4], accB[6][4];
#pragma unroll
            for (int i = 0; i < 6; i++)
#pragma unroll
                for (int j = 0; j < 4; j++) { accA[i][j] = 0.f; accB[i][j] = 0.f; }
            for (int kc = 0; kc < 128; kc += 4) {
                const int q4 = kc >> 2;
                f32x4 bA[4], bB[4];
#pragma unroll
                for (int j = 0; j < 4; j++) {
                    bA[j] = *(const f32x4*)(W1q + (q4 * 256 + c32 + 32 * j) * 4);
                    bB[j] = *(const f32x4*)(W1q + (q4 * 256 + 128 + c32 + 32 * j) * 4);
                }
#pragma unroll
                for (int i = 0; i < 6; i++) {
                    if (i < nR) {
                        f32x4 a = *(const f32x4*)(hRM + (rowBase + i) * HSTR + kc);
#pragma unroll
                        for (int j = 0; j < 4; j++)
#pragma unroll
                            for (int kk = 0; kk < 4; kk++) {
                                accA[i][j] = fmaf(a[kk], bA[j][kk], accA[i][j]);
                                accB[i][j] = fmaf(a[kk], bB[j][kk], accB[i][j]);
                            }
                    }
                }
            }
            float* hAB = reg2;
#pragma unroll
            for (int i = 0; i < 6; i++) {
                if (i < nR) {
                    int row = rowBase + i;
#pragma unroll
                    for (int j = 0; j < 4; j++) {
                        hAB[row * ABSTR + c32 + 32 * j] = accA[i][j];
                        hAB[row * ABSTR + 128 + c32 + 32 * j] = accB[i][j];
                    }
                }
            }
        }
        __syncthreads();   // B1: hAB ready

        // ---------- edge aggregation: 3 rows x 8 features per thread ----------
        float sv[3][8];
        {
            float bq[8];
#pragma unroll
            for (int j = 0; j < 8; j++) bq[j] = bm1L[f8 + j];
#pragma unroll
            for (int s = 0; s < 3; s++) {
                int row = rW + 32 * s;
                if (row >= NN) {
#pragma unroll
                    for (int j = 0; j < 8; j++) sv[s][j] = 0.f;
                    continue;
                }
                int e0 = goffL[row], e1 = goffL[row + 1];
                f32x4 hb0 = *(const f32x4*)(reg2 + row * ABSTR + 128 + f8);
                f32x4 hb1 = *(const f32x4*)(reg2 + row * ABSTR + 128 + f8 + 4);
                float hbb[8], ac[8];
#pragma unroll
                for (int j = 0; j < 4; j++) {
                    hbb[j] = hb0[j] + bq[j];
                    hbb[4 + j] = hb1[j] + bq[4 + j];
                    ac[j] = 0.f; ac[4 + j] = 0.f;
                }
                for (int e = e0; e < e1; e++) {
                    int sn = gsendL[e];
                    f32x4 av0 = *(const f32x4*)(reg2 + sn * ABSTR + f8);
                    f32x4 av1 = *(const f32x4*)(reg2 + sn * ABSTR + f8 + 4);
#pragma unroll
                    for (int j = 0; j < 4; j++) {
                        ac[j]     += fmaxf(av0[j] + hbb[j], 0.f);
                        ac[4 + j] += fmaxf(av1[j] + hbb[4 + j], 0.f);
                    }
                }
#pragma unroll
                for (int j = 0; j < 8; j++) sv[s][j] = ac[j];
            }
        }
        __syncthreads();   // B2: hAB reads done, reg2 reusable as smRM
        {
#pragma unroll
            for (int s = 0; s < 3; s++) {
                int row = rW + 32 * s;
                if (row >= NN) continue;
                f32x4 v0 = {sv[s][0], sv[s][1], sv[s][2], sv[s][3]};
                f32x4 v1 = {sv[s][4], sv[s][5], sv[s][6], sv[s][7]};
                *(f32x4*)(reg2 + row * HSTR + f8) = v0;
                *(f32x4*)(reg2 + row * HSTR + f8 + 4) = v1;
            }
        }
        __syncthreads();   // B3: smRM ready

        // ---------- GEMM2 split passes (4 cols per thread) ----------
        {
            const float* smRM = reg2;
            float rg_[6][4], z[6][4];
            // ---- pass1: rr, zz over sm (k 0..127) then h (k 128..255)
            {
                float rr[6][4], zz[6][4];
#pragma unroll
                for (int i = 0; i < 6; i++)
#pragma unroll
                    for (int j = 0; j < 4; j++) { rr[i][j] = 0.f; zz[i][j] = 0.f; }
                for (int kc = 0; kc < 128; kc += 4) {
                    const int g4 = kc >> 2;
                    f32x4 bR[4], bZ[4];
#pragma unroll
                    for (int j = 0; j < 4; j++) {
                        bR[j] = *(const f32x4*)(Wgq + (g4 * G3 + c32 + 32 * j) * 4);
                        bZ[j] = *(const f32x4*)(Wgq + (g4 * G3 + 128 + c32 + 32 * j) * 4);
                    }
#pragma unroll
                    for (int i = 0; i < 6; i++) {
                        if (i < nR) {
                            f32x4 a = *(const f32x4*)(smRM + (rowBase + i) * HSTR + kc);
#pragma unroll
                            for (int j = 0; j < 4; j++)
#pragma unroll
                                for (int kk = 0; kk < 4; kk++) {
                                    rr[i][j] = fmaf(a[kk], bR[j][kk], rr[i][j]);
                                    zz[i][j] = fmaf(a[kk], bZ[j][kk], zz[i][j]);
                                }
                        }
                    }
                }
                for (int kc = 0; kc < 128; kc += 4) {
                    const int g4 = (128 + kc) >> 2;
                    f32x4 bR[4], bZ[4];
#pragma unroll
                    for (int j = 0; j < 4; j++) {
                        bR[j] = *(const f32x4*)(Wgq + (g4 * G3 + c32 + 32 * j) * 4);
                        bZ[j] = *(const f32x4*)(Wgq + (g4 * G3 + 128 + c32 + 32 * j) * 4);
                    }
#pragma unroll
                    for (int i = 0; i < 6; i++) {
                        if (i < nR) {
                            f32x4 a = *(const f32x4*)(hRM + (rowBase + i) * HSTR + kc);
#pragma unroll
                            for (int j = 0; j < 4; j++)
#pragma unroll
                                for (int kk = 0; kk < 4; kk++) {
                                    rr[i][j] = fmaf(a[kk], bR[j][kk], rr[i][j]);
                                    zz[i][j] = fmaf(a[kk], bZ[j][kk], zz[i][j]);
                                }
                        }
                    }
                }
#pragma unroll
                for (int i = 0; i < 6; i++) {
                    if (i < nR) {
                        int row = rowBase + i;
                        float cf = (float)(goffL[row + 1] - goffL[row]);
#pragma unroll
                        for (int j = 0; j < 4; j++) {
                            int cc = c32 + 32 * j;
                            float g0 = rr[i][j] + baseL[cc] + cf * extL[cc];
                            float g1 = zz[i][j] + baseL[128 + cc] + cf * extL[128 + cc];
                            rg_[i][j] = 1.f / (1.f + __expf(-g0));
                            z[i][j]   = 1.f / (1.f + __expf(-g1));
                        }
                    }
                }
            }
            // ---- pass2a: nh over h -> tmp = rg_ * (nh + base3)
            float tmp[6][4];
            {
                float nh[6][4];
#pragma unroll
                for (int i = 0; i < 6; i++)
#pragma unroll
                    for (int j = 0; j < 4; j++) nh[i][j] = 0.f;
                for (int kc = 0; kc < 128; kc += 4) {
                    const int g4 = (128 + kc) >> 2;
                    f32x4 bN[4];
#pragma unroll
                    for (int j = 0; j < 4; j++)
                        bN[j] = *(const f32x4*)(Wgq + (g4 * G3 + 256 + c32 + 32 * j) * 4);
#pragma unroll
                    for (int i = 0; i < 6; i++) {
                        if (i < nR) {
                            f32x4 a = *(const f32x4*)(hRM + (rowBase + i) * HSTR + kc);
#pragma unroll
                            for (int j = 0; j < 4; j++)
#pragma unroll
                                for (int kk = 0; kk < 4; kk++)
                                    nh[i][j] = fmaf(a[kk], bN[j][kk], nh[i][j]);
                        }
                    }
                }
#pragma unroll
                for (int i = 0; i < 6; i++) {
                    if (i < nR) {
#pragma unroll
                        for (int j = 0; j < 4; j++)
                            tmp[i][j] = rg_[i][j] * (nh[i][j] + baseL[384 + c32 + 32 * j]);
                    }
                }
            }
            // ---- pass2b: ni over sm -> GRU epilogue
            {
                float ni[6][4];
#pragma unroll
                for (int i = 0; i < 6; i++)
#pragma unroll
                    for (int j = 0; j < 4; j++) ni[i][j] = 0.f;
                for (int kc = 0; kc < 128; kc += 4) {
                    const int g4 = kc >> 2;
                    f32x4 bN[4];
#pragma unroll
                    for (int j = 0; j < 4; j++)
                        bN[j] = *(const f32x4*)(Wgq + (g4 * G3 + 256 + c32 + 32 * j) * 4);
#pragma unroll
                    for (int i = 0; i < 6; i++) {
                        if (i < nR) {
                            f32x4 a = *(const f32x4*)(smRM + (rowBase + i) * HSTR + kc);
#pragma unroll
                            for (int j = 0; j < 4; j++)
#pragma unroll
                                for (int kk = 0; kk < 4; kk++)
                                    ni[i][j] = fmaf(a[kk], bN[j][kk], ni[i][j]);
                        }
                    }
                }
                __syncthreads();   // B4: all smRM/hRM reads done before h writes

#pragma unroll
                for (int i = 0; i < 6; i++) {
                    if (i < nR) {
                        int row = rowBase + i;
                        float cf = (float)(goffL[row + 1] - goffL[row]);
#pragma unroll
                        for (int j = 0; j < 4; j++) {
                            int cc = c32 + 32 * j;
                            float npre = ni[i][j] + baseL[256 + cc] + cf * extL[256 + cc] + tmp[i][j];
                            float ax = fabsf(npre);
                            float e  = __expf(-2.f * ax);
                            float tt = (1.f - e) / (1.f + e);
                            float n  = copysignf(tt, npre);
                            float ho = hRM[row * HSTR + cc];
                            hRM[row * HSTR + cc] = (1.f - z[i][j]) * n + z[i][j] * ho;
                        }
                    }
                }
            }
        }
        __syncthreads();   // B5: new h visible
    }

    // ======================= output head =======================
    // hid = relu(h @ W_o1^T + b_o1): thread -> cols c32+32j, its rows
    {
        float acc3[6][4];
#pragma unroll
        for (int i = 0; i < 6; i++)
#pragma unroll
            for (int j = 0; j < 4; j++) acc3[i][j] = 0.f;
        for (int kc = 0; kc < 128; kc += 4) {
            f32x4 bb[4];
#pragma unroll
            for (int j = 0; j < 4; j++)
                bb[j] = *(const f32x4*)(Wo1q + ((kc >> 2) * 128 + c32 + 32 * j) * 4);
#pragma unroll
            for (int i = 0; i < 6; i++) {
                if (i < nR) {
                    f32x4 a = *(const f32x4*)(hRM + (rowBase + i) * HSTR + kc);
#pragma unroll
                    for (int j = 0; j < 4; j++)
#pragma unroll
                        for (int kk = 0; kk < 4; kk++)
                            acc3[i][j] = fmaf(a[kk], bb[j][kk], acc3[i][j]);
                }
            }
        }
        __syncthreads();   // hRM reads done; reg2 -> hid
#pragma unroll
        for (int i = 0; i < 6; i++) {
            if (i < nR) {
                int row = rowBase + i;
#pragma unroll
                for (int j = 0; j < 4; j++) {
                    int cc = c32 + 32 * j;
                    reg2[row * HSTR + cc] = fmaxf(acc3[i][j] + b_o1[cc], 0.f);
                }
            }
        }
    }
    __syncthreads();
    // stage W_o2/b_o2 into hRM area (dead)
    {
        float* wo2L = hRM;
        float* bo2L = hRM + 1152;
        for (int i = t; i < 9 * HH; i += 512) wo2L[i] = W_o2[i];
        if (t < 9) bo2L[t] = b_o2[t];
    }
    __syncthreads();
    {
        const float* wo2L = hRM;
        const float* bo2L = hRM + 1152;
        for (int idx = t; idx < NN * 9; idx += 512) {
            int r = idx / 9, qq = idx - 9 * r;
            float acc = bo2L[qq];
            const float* hrow = reg2 + r * HSTR;
            const float* wrow = wo2L + qq * HH;
            for (int k = 0; k < HH; k++) acc = fmaf(hrow[k], wrow[k], acc);
            out[((long)b * NN + r) * 9 + qq] = acc;
        }
    }
}

// ---------------------------------------------------------------------------
extern "C" void kernel_launch(void* const* d_in, const int* in_sizes, int n_in,
                              void* d_out, int out_size, void* d_ws, size_t ws_size,
                              hipStream_t stream) {
    const float* x      = (const float*)d_in[0];
    const int* ei       = (const int*)d_in[1];
    const float* W_in   = (const float*)d_in[2];
    const float* b_in   = (const float*)d_in[3];
    const float* W_m1   = (const float*)d_in[4];
    const float* b_m1   = (const float*)d_in[5];
    const float* W_m2   = (const float*)d_in[6];
    const float* b_m2   = (const float*)d_in[7];
    const float* W_ih   = (const float*)d_in[8];
    const float* W_hh   = (const float*)d_in[9];
    const float* b_ih   = (const float*)d_in[10];
    const float* b_hh   = (const float*)d_in[11];
    const float* W_o1   = (const float*)d_in[12];
    const float* b_o1   = (const float*)d_in[13];
    const float* W_o2   = (const float*)d_in[14];
    const float* b_o2   = (const float*)d_in[15];
    float* out = (float*)d_out;

    char* ws = (char*)d_ws;
    size_t off = 0;
    auto alloc = [&](size_t bytes) -> char* {
        char* p = ws + off;
        off += (bytes + 255) & ~(size_t)255;
        return p;
    };
    float* Wc    = (float*)alloc((size_t)G3 * HH * 4);
    float* W1q   = (float*)alloc(128 * 256 * 4);
    float* Wgq   = (float*)alloc(256 * G3 * 4);
    float* Wo1q  = (float*)alloc(128 * 128 * 4);
    float* basev = (float*)alloc(512 * 4);
    float* extv  = (float*)alloc(512 * 4);
    int* goff    = (int*)alloc((NN + 1) * 4);
    int* gsend   = (int*)alloc(EE * 4);

    prep_graph<<<1, 128, 0, stream>>>(ei, goff, gsend);
    prep_wc<<<(G3 * HH + 255) / 256, 256, 0, stream>>>(W_ih, W_m2, Wc);
    prep_bias<<<2, 256, 0, stream>>>(W_ih, b_m2, b_ih, b_hh, basev, extv);
    prep_w1q<<<128, 256, 0, stream>>>(W_m1, W1q);
    prep_wgq<<<(256 * G3 + 255) / 256, 256, 0, stream>>>(Wc, W_hh, Wgq);
    prep_wo1q<<<64, 256, 0, stream>>>(W_o1, Wo1q);

    (void)hipFuncSetAttribute((const void*)fused_rrn,
                              hipFuncAttributeMaxDynamicSharedMemorySize,
                              (int)LDS_BYTES);
    fused_rrn<<<BB, 512, LDS_BYTES, stream>>>(
        x, W_in, b_in, b_m1, W1q, Wgq, basev, extv,
        Wo1q, b_o1, W_o2, b_o2, goff, gsend, out);
}